// Round 1
// 699.239 us; speedup vs baseline: 1.0044x; 1.0044x over previous
//
#include <hip/hip_runtime.h>

// out[b,g,h,w] = sum_n x[b, IDX[g,n], h, w] * w[g,n]
// IDX[g,n] = (g/4)*16 + n*4 + (g%4)   (bijection over 64 channels)
// B=8, C=64, G=16, N=4, HW=512*512.
// Pure streaming: 512 MiB read + 128 MiB write -> HBM-bound, ~107 us floor.
//
// R1: grid-stride (2048 blocks, G11), non-temporal loads/stores (zero-reuse
// streams, keep them out of L2/L3), unroll-4 for 16 in-flight loads/thread.
// With stride = 524288 = 8*HW4, hw4 is loop-invariant and bg steps by 8;
// bg/g/b/w are wave-uniform -> per-iteration overhead is pure SALU.

#define B_    8
#define C_    64
#define G_    16
#define BG_   (B_ * G_)        // 128
#define HW4_  65536            // 512*512/4 (float4 units)
#define BLOCK_ 256
#define GRID_  2048            // 8 blocks/CU * 256 CU -> full co-residency
#define BG_STEP_ ((GRID_ * BLOCK_) / HW4_)   // 8

typedef float v4f __attribute__((ext_vector_type(4)));

__global__ __launch_bounds__(BLOCK_) void binnings_kernel(
    const v4f* __restrict__ x,     // (B, C, HW4) in float4 units
    const v4f* __restrict__ w4,    // (G) : w4[g] = w[g,0..3]
    v4f* __restrict__ out)         // (B, G, HW4)
{
    const int tid = blockIdx.x * BLOCK_ + threadIdx.x;  // [0, 524288)
    const int hw4 = tid & (HW4_ - 1);                   // loop-invariant
    const int bg0 = tid >> 16;                          // [0, 8)

    #pragma unroll 4
    for (int bg = bg0; bg < BG_; bg += BG_STEP_) {
        const int g  = bg & (G_ - 1);       // wave-uniform
        const int b  = bg >> 4;             // wave-uniform
        const int c0 = ((g >> 2) << 4) + (g & 3);

        const v4f w = w4[g];                // 256 B table, stays cached

        const v4f* xp = x + ((size_t)(b * C_ + c0)) * HW4_ + hw4;
        const v4f a0 = __builtin_nontemporal_load(xp);
        const v4f a1 = __builtin_nontemporal_load(xp + (size_t)4  * HW4_);
        const v4f a2 = __builtin_nontemporal_load(xp + (size_t)8  * HW4_);
        const v4f a3 = __builtin_nontemporal_load(xp + (size_t)12 * HW4_);

        v4f o;
        o.x = a0.x * w.x + a1.x * w.y + a2.x * w.z + a3.x * w.w;
        o.y = a0.y * w.x + a1.y * w.y + a2.y * w.z + a3.y * w.w;
        o.z = a0.z * w.x + a1.z * w.y + a2.z * w.z + a3.z * w.w;
        o.w = a0.w * w.x + a1.w * w.y + a2.w * w.z + a3.w * w.w;

        __builtin_nontemporal_store(o, out + (size_t)bg * HW4_ + hw4);
    }
}

extern "C" void kernel_launch(void* const* d_in, const int* in_sizes, int n_in,
                              void* d_out, int out_size, void* d_ws, size_t ws_size,
                              hipStream_t stream) {
    const v4f* x  = (const v4f*)d_in[0];   // (8,64,512,512) f32
    const v4f* w4 = (const v4f*)d_in[1];   // (16,4,1,1) f32
    v4f* out = (v4f*)d_out;                // (8,16,512,512) f32

    binnings_kernel<<<GRID_, BLOCK_, 0, stream>>>(x, w4, out);
}